// Round 3
// baseline (324.205 us; speedup 1.0000x reference)
//
#include <hip/hip_runtime.h>
#include <hip/hip_bf16.h>

// Problem constants (fixed by setup_inputs)
#define Bsz 64
#define Pp  256
#define Dv  1024
#define Dt  768
#define Ss  512
#define NSEG 32
#define PPT  8
#define MSEG (Bsz*NSEG)     // 2048 GEMM rows (segment-summed)
#define TEMP_INV (1.0f/0.07f)

// k_prep grid roles
#define SCAN_BLOCKS 64
#define WT_BLOCKS 768       // (Dv/32)*(Dt/32)
#define LN0 (SCAN_BLOCKS + WT_BLOCKS)          // 832
#define PREP_BLOCKS (LN0 + MSEG)               // 2880

// k_mid grid roles
#define GEMM_BLOCKS 384     // (Dt/64)*(MSEG/64) = 12*32
#define EMB_BLKS 8192       // 32768 token rows / 4 rows per block
#define MID_BLOCKS (GEMM_BLOCKS + EMB_BLKS)

typedef __attribute__((ext_vector_type(8))) short short8;
typedef __attribute__((ext_vector_type(4))) float floatx4;

__device__ __forceinline__ unsigned short f2bf(float f) {
    unsigned u = __builtin_bit_cast(unsigned, f);
    u += 0x7fffu + ((u >> 16) & 1u);   // round-to-nearest-even
    return (unsigned short)(u >> 16);
}

// K1: prep (everything that depends only on inputs).
//   blocks [0, SCAN_BLOCKS):     per-row placeholder rank scan
//                                 -> gid[32768]  (-1 = valid placeholder, else wte id)
//                                 -> scat[2048]  (token pos per seg row, -1 = none)
//   blocks [SCAN, +WT_BLOCKS):   W [Dv][Dt] fp32 -> Wt bf16 [Dt][Dv] (32x32 tiles)
//   blocks [LN0, +MSEG):         LayerNorm + 8-patch segment sum -> sA bf16 [MSEG][Dv]
__global__ __launch_bounds__(512) void k_prep(const float* __restrict__ W,
                                              unsigned short* __restrict__ Wt,
                                              const float* __restrict__ x,
                                              const float* __restrict__ gamma,
                                              const float* __restrict__ beta,
                                              unsigned short* __restrict__ sA,
                                              const int* __restrict__ ids,
                                              const int* __restrict__ php,
                                              int* __restrict__ gid,
                                              int* __restrict__ scat,
                                              float* __restrict__ lossp,
                                              int* __restrict__ ctr) {
    __shared__ float smem[8 * Dv];   // 32 KB, aliased by roles
    int t = threadIdx.x;
    if (blockIdx.x < SCAN_BLOCKS) {
        // ---- placeholder rank scan for batch row b ----
        int* arr = (int*)smem;
        int b = blockIdx.x;
        if (b == 0 && t == 0) { *lossp = 0.f; *ctr = 0; }
        int ph = *php;
        int id = ids[b * Ss + t];
        int m = (id == ph) ? 1 : 0;
        arr[t] = m;
        __syncthreads();
        for (int off = 1; off < Ss; off <<= 1) {
            int v = (t >= off) ? arr[t - off] : 0;
            __syncthreads();
            arr[t] += v;
            __syncthreads();
        }
        int rank = arr[t] - 1;
        int valid = m && (rank < NSEG);
        if (t < NSEG) scat[b * NSEG + t] = -1;   // init (overwritten below)
        __syncthreads();                          // order init before scatter writes
        if (valid) scat[b * NSEG + rank] = t;     // token pos within row
        gid[b * Ss + t] = valid ? -1 : id;
        return;
    }
    if (blockIdx.x < LN0) {
        // ---- W transpose+cast: tile (k0, n0) ----
        float (*tile)[33] = (float (*)[33])smem;
        int idx = blockIdx.x - SCAN_BLOCKS;
        int k0 = (idx & 31) * 32, n0 = (idx >> 5) * 32;
        int tx = t & 31, ty = t >> 5;          // ty 0..15
        #pragma unroll
        for (int i = 0; i < 32; i += 16)
            tile[ty + i][tx] = W[(size_t)(k0 + ty + i) * Dt + n0 + tx];
        __syncthreads();
        #pragma unroll
        for (int i = 0; i < 32; i += 16)
            Wt[(size_t)(n0 + ty + i) * Dv + k0 + tx] = f2bf(tile[tx][ty + i]);
        return;
    }
    // ---- LN + segment-sum ----
    float (*sg)[Dv] = (float (*)[Dv])smem;
    int seg = blockIdx.x - LN0;            // 0..MSEG-1
    int w = t >> 6, l = t & 63;
    const float* row = x + ((size_t)seg * PPT + w) * Dv;
    float4 v[4];
    float s = 0.f, sq = 0.f;
    #pragma unroll
    for (int j = 0; j < 4; ++j) {
        v[j] = ((const float4*)row)[l + 64 * j];
        s  += v[j].x + v[j].y + v[j].z + v[j].w;
        sq += v[j].x*v[j].x + v[j].y*v[j].y + v[j].z*v[j].z + v[j].w*v[j].w;
    }
    #pragma unroll
    for (int o = 32; o; o >>= 1) { s += __shfl_down(s, o, 64); sq += __shfl_down(sq, o, 64); }
    s  = __shfl(s, 0, 64);
    sq = __shfl(sq, 0, 64);
    float mean = s * (1.0f / Dv);
    float rs = rsqrtf(sq * (1.0f / Dv) - mean * mean + 1e-5f);
    #pragma unroll
    for (int j = 0; j < 4; ++j) {
        int c4 = l + 64 * j;
        float4 g = ((const float4*)gamma)[c4];
        float4 b = ((const float4*)beta)[c4];
        float4 o;
        o.x = (v[j].x - mean) * rs * g.x + b.x;
        o.y = (v[j].y - mean) * rs * g.y + b.y;
        o.z = (v[j].z - mean) * rs * g.z + b.z;
        o.w = (v[j].w - mean) * rs * g.w + b.w;
        *(float4*)&sg[w][c4 * 4] = o;
    }
    __syncthreads();
    #pragma unroll
    for (int cc = 0; cc < 2; ++cc) {
        int c = t + cc * 512;
        float acc = 0.f;
        #pragma unroll
        for (int r = 0; r < 8; ++r) acc += sg[r][c];
        sA[(size_t)seg * Dv + c] = f2bf(acc);
    }
}

// K2: GEMM + emb-copy in ONE grid (compute-bound MFMA overlaps BW-bound copy).
//   blocks [0, GEMM_BLOCKS):  seg[2048][768] = sA@W /8 + bias; epilogue ALSO scatters
//                             each seg row to out[token] when scat[m] >= 0.
//   blocks [GEMM_BLOCKS, +EMB_BLKS): out[row] = wte[gid[row]] for gid >= 0
//                                    (valid placeholder rows left for gemm scatter)
__global__ __launch_bounds__(256) void k_mid(const unsigned short* __restrict__ A,
                                             const unsigned short* __restrict__ Wt, // [Dt][Dv]
                                             const float* __restrict__ bias,
                                             float* __restrict__ C,
                                             const int* __restrict__ gid,
                                             const int* __restrict__ scat,
                                             const float* __restrict__ wte,
                                             float* __restrict__ out) {
    __shared__ unsigned short As[64][72];
    __shared__ unsigned short Bs[64][72];
    int bid = blockIdx.x;
    int tid = threadIdx.x;
    if (bid >= GEMM_BLOCKS) {
        // ---- text_emb base copy: 4 token rows per block ----
        int base = (bid - GEMM_BLOCKS) << 2;
        #pragma unroll
        for (int k = 0; k < 3; ++k) {
            int i = tid + (k << 8);          // 0..767 over 4 rows x 192 float4
            int row = i / 192;
            int col = i - row * 192;
            int g = gid[base + row];
            if (g >= 0)
                ((float4*)(out + (size_t)(base + row) * Dt))[col] =
                    ((const float4*)(wte + (size_t)g * Dt))[col];
        }
        return;
    }
    int n0 = (bid % 12) * 64;
    int m0 = (bid / 12) * 64;
    int wv = tid >> 6, lane = tid & 63;
    int lrow = lane & 15, lk = (lane >> 4) * 8;
    int sm = tid >> 2;            // 0..63 staging row
    int sk = (tid & 3) * 16;      // 0,16,32,48 (elements)
    const unsigned short* Ap = A  + (size_t)(m0 + sm) * Dv + sk;
    const unsigned short* Bp = Wt + (size_t)(n0 + sm) * Dv + sk;
    uint4 a0 = *(const uint4*)Ap, a1 = *(const uint4*)(Ap + 8);
    uint4 b0 = *(const uint4*)Bp, b1 = *(const uint4*)(Bp + 8);
    floatx4 acc[4] = {};
    for (int k0 = 0; k0 < Dv; k0 += 64) {
        *(uint4*)&As[sm][sk]     = a0;
        *(uint4*)&As[sm][sk + 8] = a1;
        *(uint4*)&Bs[sm][sk]     = b0;
        *(uint4*)&Bs[sm][sk + 8] = b1;
        __syncthreads();
        if (k0 + 64 < Dv) {
            Ap += 64; Bp += 64;
            a0 = *(const uint4*)Ap; a1 = *(const uint4*)(Ap + 8);
            b0 = *(const uint4*)Bp; b1 = *(const uint4*)(Bp + 8);
        }
        #pragma unroll
        for (int ks = 0; ks < 2; ++ks) {
            short8 af = *(const short8*)&As[16 * wv + lrow][ks * 32 + lk];
            #pragma unroll
            for (int ts = 0; ts < 4; ++ts) {
                short8 bf = *(const short8*)&Bs[16 * ts + lrow][ks * 32 + lk];
                acc[ts] = __builtin_amdgcn_mfma_f32_16x16x32_bf16(af, bf, acc[ts], 0, 0, 0);
            }
        }
        __syncthreads();
    }
    #pragma unroll
    for (int r = 0; r < 4; ++r) {
        int m = m0 + 16 * wv + (lane >> 4) * 4 + r;
        int sc = scat[m];
        float* orow = out + ((size_t)(m >> 5) * Ss + (sc < 0 ? 0 : sc)) * Dt;
        #pragma unroll
        for (int ts = 0; ts < 4; ++ts) {
            int n = n0 + 16 * ts + lrow;
            float val = acc[ts][r] * 0.125f + bias[n];
            C[(size_t)m * Dt + n] = val;
            if (sc >= 0) orow[n] = val;
        }
    }
}

// K3: pool + normalize + full contrastive loss in ONE launch.
// 64 blocks (guaranteed co-resident on 256 CUs) with a device-scope spin barrier
// between "write nrm[b]" and "read all nrm rows".
// loss = mean_i(lse_i - sim_ii) == (ce_row+ce_col)/2 since sim is symmetric.
__global__ __launch_bounds__(512) void k_tail(const float* __restrict__ seg,
                                              float* __restrict__ nrm,
                                              float* __restrict__ lossp,
                                              int* __restrict__ ctr) {
    __shared__ float ls[Dt];
    __shared__ float simrow[64];
    __shared__ float red[8];
    int b = blockIdx.x, t = threadIdx.x;
    // ---- pool: mean over 32 seg rows, L2-normalize ----
    const float* base = seg + (size_t)b * NSEG * Dt;
    float p0 = 0.f, p1 = 0.f;
    for (int g = 0; g < NSEG; ++g) p0 += base[(size_t)g * Dt + t];
    if (t < 256)
        for (int g = 0; g < NSEG; ++g) p1 += base[(size_t)g * Dt + 512 + t];
    p0 *= (1.0f / NSEG); p1 *= (1.0f / NSEG);
    float sq = p0 * p0 + (t < 256 ? p1 * p1 : 0.f);
    #pragma unroll
    for (int o = 32; o; o >>= 1) sq += __shfl_down(sq, o, 64);
    int wv = t >> 6, ln = t & 63;
    if (ln == 0) red[wv] = sq;
    __syncthreads();
    if (t == 0) {
        float S = 0.f;
        #pragma unroll
        for (int i = 0; i < 8; ++i) S += red[i];
        red[0] = 1.0f / sqrtf(S);
    }
    __syncthreads();
    float inv = red[0];
    float v0 = p0 * inv;
    nrm[(size_t)b * Dt + t] = v0;
    ls[t] = v0;
    if (t < 256) {
        float v1 = p1 * inv;
        nrm[(size_t)b * Dt + 512 + t] = v1;
        ls[512 + t] = v1;
    }
    // ---- grid barrier: all 64 blocks resident -> spin on device-scope counter ----
    __threadfence();                 // release: nrm writes visible device-wide
    __syncthreads();
    if (t == 0) {
        __hip_atomic_fetch_add(ctr, 1, __ATOMIC_ACQ_REL, __HIP_MEMORY_SCOPE_AGENT);
        while (__hip_atomic_load(ctr, __ATOMIC_RELAXED, __HIP_MEMORY_SCOPE_AGENT) < 64)
            __builtin_amdgcn_s_sleep(2);
    }
    __syncthreads();
    __threadfence();                 // acquire side
    // ---- sim row b, logsumexp, accumulate loss ----
    int jj = t >> 3, q = t & 7;                 // 64 j-rows x 8 lanes
    const float* nj = nrm + (size_t)jj * Dt + q * 96;
    const float* li = ls + q * 96;
    float s = 0.f;
    for (int d = 0; d < 96; ++d) s += li[d] * nj[d];
    s += __shfl_down(s, 4, 8);
    s += __shfl_down(s, 2, 8);
    s += __shfl_down(s, 1, 8);
    if (q == 0) simrow[jj] = s * TEMP_INV;
    __syncthreads();
    if (t < 64) {
        // |sim| <= 14.3 -> exp <= 1.6e6, no max-shift needed in fp32
        float sum = expf(simrow[t]);
        #pragma unroll
        for (int o = 32; o; o >>= 1) sum += __shfl_down(sum, o, 64);
        if (t == 0)
            atomicAdd(lossp, (logf(sum) - simrow[b]) * (1.0f / 64.0f));
    }
}

extern "C" void kernel_launch(void* const* d_in, const int* in_sizes, int n_in,
                              void* d_out, int out_size, void* d_ws, size_t ws_size,
                              hipStream_t stream) {
    const float* vis   = (const float*)d_in[0];
    const float* gamma = (const float*)d_in[1];
    const float* beta  = (const float*)d_in[2];
    const float* W     = (const float*)d_in[3];
    const float* bproj = (const float*)d_in[4];
    const float* wte   = (const float*)d_in[5];
    const int*   ids   = (const int*)d_in[6];
    const int*   php   = (const int*)d_in[7];

    char* ws = (char*)d_ws;
    unsigned short* sA   = (unsigned short*)(ws + 0);        // 2048*1024*2 = 4194304
    unsigned short* Wt   = (unsigned short*)(ws + 4194304);  // 768*1024*2  = 1572864
    float*          seg  = (float*)(ws + 5767168);           // 2048*768*4  = 6291456
    float*          nrm  = (float*)(ws + 12058624);          // 64*768*4    = 196608
    int*            gid  = (int*)(ws + 12255232);            // 32768*4     = 131072
    int*            scat = (int*)(ws + 12386304);            // 2048*4      = 8192
    int*            ctr  = (int*)(ws + 12394496);            // 4

    float* out = (float*)d_out;
    float* lossp = out + (size_t)Bsz * Ss * Dt;

    k_prep<<<PREP_BLOCKS, 512, 0, stream>>>(W, Wt, vis, gamma, beta, sA,
                                            ids, php, gid, scat, lossp, ctr);
    k_mid <<<MID_BLOCKS, 256, 0, stream>>>(sA, Wt, bproj, seg, gid, scat, wte, out);
    k_tail<<<64, 512, 0, stream>>>(seg, nrm, lossp, ctr);
}